// Round 20
// baseline (1016.180 us; speedup 1.0000x reference)
//
#include <hip/hip_runtime.h>
#include <hip/hip_bf16.h>
#include <math.h>

#define B_ 512
#define E_ 256
#define H_ 512
#define V_ 4096
#define T_ 18
#define L_ 20
#define MARGIN_ 0.04f
#define CCAP_ 64

typedef __attribute__((ext_vector_type(8))) short bf16x8;
typedef __attribute__((ext_vector_type(4))) float f32x4;

// ========== prep: cat fp32 + WoutB bf16 (float4-vectorized) ==========
__global__ __launch_bounds__(256) void kprep32(const float* __restrict__ pa,
                                               const float* __restrict__ pb,
                                               const float* __restrict__ Wout,
                                               float* __restrict__ cat,
                                               __hip_bfloat16* __restrict__ WB) {
  int idx = blockIdx.x * 256 + threadIdx.x;      // < 655360 quads
  if (idx < 131072) {
    int e0 = idx * 4;
    int b = e0 >> 10, k = e0 & 1023;             // quads never straddle 512
    float4 v = (k < 512) ? *reinterpret_cast<const float4*>(pa + (size_t)b * 512 + k)
                         : *reinterpret_cast<const float4*>(pb + (size_t)b * 512 + (k - 512));
    *reinterpret_cast<float4*>(cat + e0) = v;
  } else {
    int e0 = (idx - 131072) * 4;                 // < 2097152
    float4 w = *reinterpret_cast<const float4*>(Wout + e0);
    __hip_bfloat16 b0 = __float2bfloat16(w.x), b1 = __float2bfloat16(w.y);
    __hip_bfloat16 b2 = __float2bfloat16(w.z), b3 = __float2bfloat16(w.w);
    ushort4 o;
    o.x = *reinterpret_cast<unsigned short*>(&b0);
    o.y = *reinterpret_cast<unsigned short*>(&b1);
    o.z = *reinterpret_cast<unsigned short*>(&b2);
    o.w = *reinterpret_cast<unsigned short*>(&b3);
    *reinterpret_cast<ushort4*>(WB + e0) = o;
  }
}

// ===== fp32 GEMM, 128x128 tile, 8x8/thread, split-K (setup + gh0) =====
__global__ __launch_bounds__(256) void sgemm128(const float* __restrict__ A,
                                                const float* __restrict__ W,
                                                float* __restrict__ P,
                                                int N, int lda, int kPer) {
  __shared__ float As[16][132];
  __shared__ float Bs[16][132];
  const int tid = threadIdx.x;
  const int tx = tid & 15, ty = tid >> 4;
  const int bn = blockIdx.x * 128, bm = blockIdx.y * 128;
  const int k0 = blockIdx.z * kPer;
  const size_t pOff = (size_t)blockIdx.z * (size_t)gridDim.y * 128 * N;
  const int r1 = tid >> 2;
  const int kq = (tid & 3) * 4;

  float acc[8][8] = {};
  for (int kb = 0; kb < kPer; kb += 16) {
    const float* Ap = A + (size_t)(bm + r1) * lda + k0 + kb + kq;
    const float* Wp = W + (size_t)(bn + r1) * lda + k0 + kb + kq;
    float4 a1 = *reinterpret_cast<const float4*>(Ap);
    float4 a2 = *reinterpret_cast<const float4*>(Ap + (size_t)64 * lda);
    float4 b1 = *reinterpret_cast<const float4*>(Wp);
    float4 b2 = *reinterpret_cast<const float4*>(Wp + (size_t)64 * lda);
    As[kq + 0][r1] = a1.x; As[kq + 1][r1] = a1.y;
    As[kq + 2][r1] = a1.z; As[kq + 3][r1] = a1.w;
    As[kq + 0][r1 + 64] = a2.x; As[kq + 1][r1 + 64] = a2.y;
    As[kq + 2][r1 + 64] = a2.z; As[kq + 3][r1 + 64] = a2.w;
    Bs[kq + 0][r1] = b1.x; Bs[kq + 1][r1] = b1.y;
    Bs[kq + 2][r1] = b1.z; Bs[kq + 3][r1] = b1.w;
    Bs[kq + 0][r1 + 64] = b2.x; Bs[kq + 1][r1 + 64] = b2.y;
    Bs[kq + 2][r1 + 64] = b2.z; Bs[kq + 3][r1 + 64] = b2.w;
    __syncthreads();
#pragma unroll
    for (int kk = 0; kk < 16; ++kk) {
      float a[8], b[8];
#pragma unroll
      for (int i = 0; i < 8; ++i) a[i] = As[kk][ty * 8 + i];
#pragma unroll
      for (int j = 0; j < 8; ++j) b[j] = Bs[kk][tx * 8 + j];
#pragma unroll
      for (int i = 0; i < 8; ++i)
#pragma unroll
        for (int j = 0; j < 8; ++j) acc[i][j] = fmaf(a[i], b[j], acc[i][j]);
    }
    __syncthreads();
  }
#pragma unroll
  for (int i = 0; i < 8; ++i) {
    size_t r = (size_t)(bm + ty * 8 + i);
    float4 v0 = make_float4(acc[i][0], acc[i][1], acc[i][2], acc[i][3]);
    float4 v1 = make_float4(acc[i][4], acc[i][5], acc[i][6], acc[i][7]);
    float4* dst = reinterpret_cast<float4*>(P + pOff + r * N + bn + tx * 8);
    dst[0] = v0;
    dst[1] = v1;
  }
}

// ======== h0 = sum of 8 partials + b_init (fp64 sum); fp32 + bf16 out ======
__global__ __launch_bounds__(256) void reduceH0(const float* __restrict__ parts,
                                                const float* __restrict__ binit,
                                                float* __restrict__ h,
                                                __hip_bfloat16* __restrict__ hB) {
  int i = blockIdx.x * 256 + threadIdx.x;
  double s = (double)binit[i & 511];
#pragma unroll
  for (int c = 0; c < 8; ++c) s += (double)parts[(size_t)c * 262144 + i];
  float f = (float)s;
  h[i] = f;
  hB[i] = __float2bfloat16(f);
}

// ---------------- phase bodies ----------------
__device__ __forceinline__ void gh_gemm_body(const float* __restrict__ h,
                                             const float* __restrict__ Whh,
                                             float* __restrict__ ghP,
                                             int gid, int tid, char* smemRaw) {
  float (*As)[132] = reinterpret_cast<float(*)[132]>(smemRaw);
  float (*Bs)[132] = reinterpret_cast<float(*)[132]>(smemRaw + 8448);
  const int tx = tid & 15, ty = tid >> 4;
  const int bx = gid % 12, by = (gid / 12) & 3, bz = gid / 48;
  const int bn = bx * 128, bm = by * 128;
  const int k0 = bz * 64;
  const size_t pOff = (size_t)bz * 786432;
  const int r1 = tid >> 2, kq = (tid & 3) * 4;
  float acc[8][8] = {};
  for (int kb = 0; kb < 64; kb += 16) {
    const float* Ap = h   + (size_t)(bm + r1) * H_ + k0 + kb + kq;
    const float* Wp = Whh + (size_t)(bn + r1) * H_ + k0 + kb + kq;
    float4 a1 = *reinterpret_cast<const float4*>(Ap);
    float4 a2 = *reinterpret_cast<const float4*>(Ap + (size_t)64 * H_);
    float4 b1 = *reinterpret_cast<const float4*>(Wp);
    float4 b2 = *reinterpret_cast<const float4*>(Wp + (size_t)64 * H_);
    As[kq + 0][r1] = a1.x; As[kq + 1][r1] = a1.y;
    As[kq + 2][r1] = a1.z; As[kq + 3][r1] = a1.w;
    As[kq + 0][r1 + 64] = a2.x; As[kq + 1][r1 + 64] = a2.y;
    As[kq + 2][r1 + 64] = a2.z; As[kq + 3][r1 + 64] = a2.w;
    Bs[kq + 0][r1] = b1.x; Bs[kq + 1][r1] = b1.y;
    Bs[kq + 2][r1] = b1.z; Bs[kq + 3][r1] = b1.w;
    Bs[kq + 0][r1 + 64] = b2.x; Bs[kq + 1][r1 + 64] = b2.y;
    Bs[kq + 2][r1 + 64] = b2.z; Bs[kq + 3][r1 + 64] = b2.w;
    __syncthreads();
#pragma unroll
    for (int kk = 0; kk < 16; ++kk) {
      float a[8], b[8];
#pragma unroll
      for (int i = 0; i < 8; ++i) a[i] = As[kk][ty * 8 + i];
#pragma unroll
      for (int j = 0; j < 8; ++j) b[j] = Bs[kk][tx * 8 + j];
#pragma unroll
      for (int i = 0; i < 8; ++i)
#pragma unroll
        for (int j = 0; j < 8; ++j) acc[i][j] = fmaf(a[i], b[j], acc[i][j]);
    }
    __syncthreads();
  }
#pragma unroll
  for (int i = 0; i < 8; ++i) {
    size_t r = (size_t)(bm + ty * 8 + i);
    float4 v0 = make_float4(acc[i][0], acc[i][1], acc[i][2], acc[i][3]);
    float4 v1 = make_float4(acc[i][4], acc[i][5], acc[i][6], acc[i][7]);
    float4* dst = reinterpret_cast<float4*>(ghP + pOff + r * 1536 + bn + tx * 8);
    dst[0] = v0;
    dst[1] = v1;
  }
}

// ====== screen: bf16 MFMA + bout + fp32 gumbel -> scores; per-block max =====
__device__ __forceinline__ void screen_body(const __hip_bfloat16* __restrict__ hB,
                                            const __hip_bfloat16* __restrict__ WoutB,
                                            const float* __restrict__ bout,
                                            const float* __restrict__ u,   // step slice
                                            float* __restrict__ loP,
                                            float* __restrict__ bMax,
                                            int bid, int tid) {
  const int wave = tid >> 6, lane = tid & 63;
  const int bx = bid & 63, by = bid >> 6;
  const int bm = by * 64 + wave * 16;
  const int bn = bx * 64;
  const int rA = lane & 15, g = lane >> 4;
  const __hip_bfloat16* ha = hB + (size_t)(bm + rA) * H_ + g * 8;
  const __hip_bfloat16* wb = WoutB + (size_t)(bn + rA) * H_ + g * 8;
  f32x4 acc[4] = {};
  for (int k0 = 0; k0 < H_; k0 += 32) {
    bf16x8 a = *reinterpret_cast<const bf16x8*>(ha + k0);
#pragma unroll
    for (int j = 0; j < 4; ++j) {
      bf16x8 b = *reinterpret_cast<const bf16x8*>(wb + (size_t)j * 16 * H_ + k0);
      acc[j] = __builtin_amdgcn_mfma_f32_16x16x32_bf16(a, b, acc[j], 0, 0, 0);
    }
  }
  float bj[4];
#pragma unroll
  for (int j = 0; j < 4; ++j) bj[j] = bout[bn + j * 16 + rA];
#pragma unroll
  for (int r = 0; r < 4; ++r) {
    int row = bm + g * 4 + r;
    const float* ur = u + (size_t)row * V_ + bn;
    float m = -1e30f;
#pragma unroll
    for (int j = 0; j < 4; ++j) {
      float s = acc[j][r] + bj[j] - logf(-logf(ur[j * 16 + rA]));
      loP[(size_t)row * V_ + bn + j * 16 + rA] = s;
      m = fmaxf(m, s);
    }
    // max over the 16 lanes of this g-group (xor hops stay in-group)
#pragma unroll
    for (int off = 1; off < 16; off <<= 1) m = fmaxf(m, __shfl_xor(m, off, 64));
    if (rA == 0) bMax[(size_t)row * 64 + bx] = m;
  }
}

// ====== pick v2: block-max screen -> tiny scan; fallback = R19 exact path ===
__device__ __forceinline__ int pick_body(const float* __restrict__ loP,
                                         const float* __restrict__ bMax,
                                         const float* __restrict__ h,
                                         const float* __restrict__ Wout,
                                         const float* __restrict__ bout,
                                         const float* __restrict__ ub,
                                         int bid, int tid, char* smemRaw) {
  double* sd    = reinterpret_cast<double*>(smemRaw);            // [4]
  double* bestS = reinterpret_cast<double*>(smemRaw + 32);
  int*    bestV = reinterpret_cast<int*>(smemRaw + 40);
  int*    sNcb  = reinterpret_cast<int*>(smemRaw + 44);
  float*  sRow  = reinterpret_cast<float*>(smemRaw + 48);
  float*  swv   = reinterpret_cast<float*>(smemRaw + 56);        // [4]
  int*    swi   = reinterpret_cast<int*>(smemRaw + 72);          // [4]
  int*    sct   = reinterpret_cast<int*>(smemRaw + 88);          // [4]
  int*    candB = reinterpret_cast<int*>(smemRaw + 104);         // [64]
  int*    candV = reinterpret_cast<int*>(smemRaw + 360);         // [64]
  int*    pre   = reinterpret_cast<int*>(smemRaw + 640);         // [256]
  const int lane = tid & 63, wv = tid >> 6;
  const float* l0 = loP + (size_t)bid * V_;

  // wave 0: row max over 64 block-maxes + candidate-block list
  if (wv == 0) {
    float bm = bMax[(size_t)bid * 64 + lane];
    float m = bm;
#pragma unroll
    for (int off = 1; off < 64; off <<= 1) m = fmaxf(m, __shfl_xor(m, off, 64));
    unsigned long long mask = __ballot(bm >= m - MARGIN_);
    int pos = __popcll(mask & ((1ull << lane) - 1ull));
    if (bm >= m - MARGIN_) candB[pos] = lane;
    if (lane == 0) { *sRow = m; *sNcb = __popcll(mask); }
  }
  __syncthreads();
  float smax = *sRow;
  int ncb = *sNcb;

  // scan candidate blocks only (superset guarantee: any in-margin element's
  // block has blockmax >= smax - MARGIN)
  float best = -1e30f; int bi = 0x7fffffff; int cnt = 0;
  for (int e = tid; e < ncb * 64; e += 256) {
    int v = candB[e >> 6] * 64 + (e & 63);
    float s = l0[v];
    if (s > best || (s == best && v < bi)) { best = s; bi = v; }
    if (s >= smax - MARGIN_) ++cnt;
  }
#pragma unroll
  for (int off = 1; off < 64; off <<= 1) {
    float ov = __shfl_xor(best, off, 64);
    int   oi = __shfl_xor(bi,  off, 64);
    if (ov > best || (ov == best && oi < bi)) { best = ov; bi = oi; }
    cnt += __shfl_xor(cnt, off, 64);
  }
  if (lane == 0) { swv[wv] = best; swi[wv] = bi; sct[wv] = cnt; }
  __syncthreads();
  float gmax = swv[0]; int amax = swi[0];
#pragma unroll
  for (int w = 1; w < 4; ++w) {
    float ov = swv[w]; int oi = swi[w];
    if (ov > gmax || (ov == gmax && oi < amax)) { gmax = ov; amax = oi; }
  }
  int tot = sct[0] + sct[1] + sct[2] + sct[3];

  int tok;
  if (tot == 1) {
    tok = amax;                                   // unique in margin -> exact
  } else if (tot <= CCAP_) {
    // R19-exact fallback: full scan builds candV, then fp64 candidate rescore
    float sloc[16];
#pragma unroll
    for (int i = 0; i < 16; ++i) sloc[i] = l0[tid + 256 * i];
    int lv[16];
    int cc = 0;
#pragma unroll
    for (int i = 0; i < 16; ++i)
      if (sloc[i] >= gmax - MARGIN_) { if (cc < 16) lv[cc] = tid + 256 * i; ++cc; }
    pre[tid] = cc;
    __syncthreads();
    for (int off = 1; off < 256; off <<= 1) {
      int vv = (tid >= off) ? pre[tid - off] : 0;
      __syncthreads();
      pre[tid] += vv;
      __syncthreads();
    }
    int base = pre[tid] - cc;
    for (int q = 0; q < cc; ++q) candV[base + q] = lv[q];
    if (tid == 0) { *bestS = -1e300; *bestV = 0x7fffffff; }
    __syncthreads();
    const float* hb = h + (size_t)bid * H_;
    for (int ci = 0; ci < tot; ++ci) {
      int v = candV[ci];
      const float* wr = Wout + (size_t)v * H_;
      double p = (double)hb[tid] * (double)wr[tid]
               + (double)hb[tid + 256] * (double)wr[tid + 256];
#pragma unroll
      for (int off = 1; off < 64; off <<= 1) p += __shfl_xor(p, off, 64);
      if (lane == 0) sd[wv] = p;
      __syncthreads();
      if (tid == 0) {
        double s = sd[0] + sd[1] + sd[2] + sd[3]
                 + (double)bout[v] - log(-log((double)ub[v]));
        if (s > *bestS || (s == *bestS && v < *bestV)) { *bestS = s; *bestV = v; }
      }
      __syncthreads();
    }
    tok = *bestV;
  } else {
    // safety net: full fp64 rescore (statistically unreachable)
    const float* hb = h + (size_t)bid * H_;
    double dbest = -1e300; int dbi = 0x7fffffff;
    for (int i = 0; i < 16; ++i) {
      int v = tid + 256 * i;
      const float* wr = Wout + (size_t)v * H_;
      double dot = 0.0;
      for (int k = 0; k < H_; ++k) dot = fma((double)hb[k], (double)wr[k], dot);
      double s = dot + (double)bout[v] - log(-log((double)ub[v]));
      if (s > dbest) { dbest = s; dbi = v; }
    }
#pragma unroll
    for (int off = 1; off < 64; off <<= 1) {
      double od = __shfl_xor(dbest, off, 64);
      int    oi = __shfl_xor(dbi,  off, 64);
      if (od > dbest || (od == dbest && oi < dbi)) { dbest = od; dbi = oi; }
    }
    if (lane == 0) { sd[wv] = dbest; pre[wv] = dbi; }
    __syncthreads();
    double bs = sd[0]; int bv = pre[0];
#pragma unroll
    for (int w = 1; w < 4; ++w) {
      if (sd[w] > bs || (sd[w] == bs && pre[w] < bv)) { bs = sd[w]; bv = pre[w]; }
    }
    tok = bv;
  }
  return tok;
}

// ===== K0: standalone gates (initial step, tok = SOS) =====
__global__ __launch_bounds__(256) void gates_init(const float* __restrict__ ghP,
                                                  const float* __restrict__ giP,
                                                  const float* __restrict__ bih,
                                                  const float* __restrict__ bhh,
                                                  float* __restrict__ h,
                                                  __hip_bfloat16* __restrict__ hB) {
  const int bid = blockIdx.x, tid = threadIdx.x;
  const float* g0 = giP + (size_t)1 * 1536;
  size_t base = (size_t)bid * 1536;
#pragma unroll
  for (int c = 0; c < 2; ++c) {
    int j = c * 256 + tid;
    int idx = bid * 512 + j;
    double gr = (double)bhh[j], gz = (double)bhh[512 + j], gn = (double)bhh[1024 + j];
#pragma unroll
    for (int s = 0; s < 8; ++s) {
      const float* p = ghP + (size_t)s * 786432 + base;
      gr += (double)p[j]; gz += (double)p[512 + j]; gn += (double)p[1024 + j];
    }
    float ir  = g0[j]        + bih[j];
    float iz  = g0[512 + j]  + bih[512 + j];
    float inn = g0[1024 + j] + bih[1024 + j];
    float r = 1.f / (1.f + expf(-(ir + (float)gr)));
    float z = 1.f / (1.f + expf(-(iz + (float)gz)));
    float n = tanhf(inn + r * (float)gn);
    float hn = (1.f - z) * n + z * h[idx];
    h[idx] = hn;
    hB[idx] = __float2bfloat16(hn);
  }
}

// ===== K1: gh GEMM (blocks 0..383) + screen w/ scores+blockmax (384..895) ====
__global__ __launch_bounds__(256) void fusedA(const float* __restrict__ h,
                                              const float* __restrict__ Whh,
                                              const __hip_bfloat16* __restrict__ hB,
                                              const __hip_bfloat16* __restrict__ WoutB,
                                              const float* __restrict__ bout,
                                              const float* __restrict__ u,   // step slice
                                              float* __restrict__ ghP,
                                              float* __restrict__ loP,
                                              float* __restrict__ bMax,
                                              int doGemm) {
  __shared__ __align__(16) char smemRaw[16896];
  const int bid = blockIdx.x, tid = threadIdx.x;
  if (bid < 384) {
    if (doGemm) gh_gemm_body(h, Whh, ghP, bid, tid, smemRaw);
  } else {
    screen_body(hB, WoutB, bout, u, loP, bMax, bid - 384, tid);
  }
}

// ===== K2: hoisted ghP sums -> pick tok(t) -> finish gates(t+1) =====
__global__ __launch_bounds__(256) void fusedB(const float* __restrict__ loP,
                                              const float* __restrict__ bMax,
                                              float* __restrict__ h,
                                              const float* __restrict__ Wout,
                                              const float* __restrict__ bout,
                                              const float* __restrict__ u,   // step slice
                                              const float* __restrict__ ghP,
                                              const float* __restrict__ giP,
                                              const float* __restrict__ bih,
                                              const float* __restrict__ bhh,
                                              __hip_bfloat16* __restrict__ hB,
                                              int* __restrict__ toks,
                                              int t, int doGates) {
  __shared__ __align__(16) char smemRaw[2048];
  const int bid = blockIdx.x, tid = threadIdx.x;
  const int j0 = tid, j1 = 256 + tid;
  // hoisted gh partial sums (token-independent; same order as gates)
  double gr0 = (double)bhh[j0], gz0 = (double)bhh[512 + j0], gn0 = (double)bhh[1024 + j0];
  double gr1 = (double)bhh[j1], gz1 = (double)bhh[512 + j1], gn1 = (double)bhh[1024 + j1];
  if (doGates) {
    size_t base = (size_t)bid * 1536;
#pragma unroll
    for (int s = 0; s < 8; ++s) {
      const float* p = ghP + (size_t)s * 786432 + base;
      gr0 += (double)p[j0]; gz0 += (double)p[512 + j0]; gn0 += (double)p[1024 + j0];
      gr1 += (double)p[j1]; gz1 += (double)p[512 + j1]; gn1 += (double)p[1024 + j1];
    }
  }
  const float* ub = u + (size_t)bid * V_;
  int tok = pick_body(loP, bMax, h, Wout, bout, ub, bid, tid, smemRaw);
  if (tid == 0) toks[t * B_ + bid] = tok;
  if (doGates) {
    const float* g0 = giP + (size_t)tok * 1536;
    {
      int idx = bid * 512 + j0;
      float ir  = g0[j0]        + bih[j0];
      float iz  = g0[512 + j0]  + bih[512 + j0];
      float inn = g0[1024 + j0] + bih[1024 + j0];
      float r = 1.f / (1.f + expf(-(ir + (float)gr0)));
      float z = 1.f / (1.f + expf(-(iz + (float)gz0)));
      float n = tanhf(inn + r * (float)gn0);
      float hn = (1.f - z) * n + z * h[idx];
      h[idx] = hn;
      hB[idx] = __float2bfloat16(hn);
    }
    {
      int idx = bid * 512 + j1;
      float ir  = g0[j1]        + bih[j1];
      float iz  = g0[512 + j1]  + bih[512 + j1];
      float inn = g0[1024 + j1] + bih[1024 + j1];
      float r = 1.f / (1.f + expf(-(ir + (float)gr1)));
      float z = 1.f / (1.f + expf(-(iz + (float)gz1)));
      float n = tanhf(inn + r * (float)gn1);
      float hn = (1.f - z) * n + z * h[idx];
      h[idx] = hn;
      hB[idx] = __float2bfloat16(hn);
    }
  }
}

// ============== final: zero + one-hot scatter + SOS/EOS, fp32 ==============
__global__ __launch_bounds__(256) void kfinal32(float* __restrict__ out,
                                                const int* __restrict__ toks) {
  size_t c = (size_t)blockIdx.x * 256 + threadIdx.x;
  size_t e0 = c * 4;
  int v0 = (int)(e0 & (size_t)(V_ - 1));
  size_t row = e0 >> 12;
  int p = (int)(row % L_);
  int b = (int)(row / L_);
  int tok;
  if (p == 0)           tok = 1;
  else if (p == L_ - 1) tok = 2;
  else                  tok = toks[(p - 1) * B_ + b];
  float4 val = make_float4(0.f, 0.f, 0.f, 0.f);
  int d = tok - v0;
  if (d >= 0 && d < 4) {
    if (d == 0) val.x = 1.f; else if (d == 1) val.y = 1.f;
    else if (d == 2) val.z = 1.f; else val.w = 1.f;
  }
  reinterpret_cast<float4*>(out)[c] = val;
}

// ---------------- environment markers ----------------
__global__ void kmark_ws(float* out) {
  if (threadIdx.x == 0) out[0] = 16.0f;
}
__global__ void kmark_resolver(float* out) {
  if (threadIdx.x == 0) out[2] = 11.0f;
}

// ================================ launch ================================
extern "C" void kernel_launch(void* const* d_in, const int* in_sizes, int n_in,
                              void* d_out, int out_size, void* d_ws, size_t ws_size,
                              hipStream_t stream) {
  static const int EXPECT[12] = {262144, 262144, 524288, 512, 393216, 786432,
                                 1536, 1536, 2097152, 4096, 1048576, 37748736};
  const float* R[12];
  bool resolved = (n_in == 12);
  if (resolved) {
    bool used[12] = {};
    for (int i = 0; i < 12; ++i) {
      int f = -1;
      for (int j = 0; j < 12; ++j)
        if (!used[j] && in_sizes[j] == EXPECT[i]) { f = j; break; }
      if (f < 0) { resolved = false; break; }
      used[f] = true;
      R[i] = (const float*)d_in[f];
    }
  }
  if (!resolved)
    for (int i = 0; i < 12 && i < n_in; ++i) R[i] = (const float*)d_in[i];

  const float *pa = R[0], *pb = R[1], *Winit = R[2], *binit = R[3],
              *Wih = R[4], *Whh = R[5], *bih = R[6], *bhh = R[7],
              *Wout = R[8], *bout = R[9], *emb = R[10], *ug = R[11];
  float* out = (float*)d_out;

  const size_t TOK_BYTES = (size_t)T_ * B_ * sizeof(int);   // 36864
  if (ws_size < TOK_BYTES) { kmark_ws<<<1, 64, 0, stream>>>(out); return; }
  int* toks = (int*)d_ws;

  // scratch: h | giP | ghP(8; aliases cat+h0P pre-loop) | loP | hB | WoutB | bMax
  const size_t SC_FLOATS = 16154624;
  float* sc;
  if (ws_size >= 40960 + SC_FLOATS * sizeof(float)) {
    sc = (float*)((char*)d_ws + 40960);
  } else {
    sc = (float*)d_out;   // head of 167.8 MB out; kfinal32 rebuilds last
  }
  float* h    = sc;                                   // 262,144
  float* giP  = sc + 262144;                          // 6,291,456 (4096x1536)
  float* ghP  = sc + 6553600;                         // 6,291,456 (8 x 512x1536)
  float* loP  = sc + 12845056;                        // 2,097,152 (512x4096)
  __hip_bfloat16* hB    = (__hip_bfloat16*)(sc + 14942208);   // 262,144 bf16
  __hip_bfloat16* WoutB = (__hip_bfloat16*)(sc + 15073280);   // 2,097,152 bf16
  float* bMax = sc + 16121856;                        // 32,768 (512 x 64)
  float* cat  = ghP;                                  // pre-loop only
  float* h0P  = ghP + 524288;                         // pre-loop only

  // ---- setup ----
  kprep32<<<2560, 256, 0, stream>>>(pa, pb, Wout, cat, WoutB);
  sgemm128<<<dim3(4, 4, 8), 256, 0, stream>>>(cat, Winit, h0P, 512, 1024, 128);
  reduceH0<<<1024, 256, 0, stream>>>(h0P, binit, h, hB);
  sgemm128<<<dim3(12, 32, 1), 256, 0, stream>>>(emb, Wih, giP, 1536, 256, 256);
  // gh(h_0) then gates(SOS) -> h_1
  sgemm128<<<dim3(12, 4, 8), 256, 0, stream>>>(h, Whh, ghP, 1536, 512, 64);
  gates_init<<<512, 256, 0, stream>>>(ghP, giP, bih, bhh, h, hB);

  // ---- decode loop: 2 launches per step ----
  for (int t = 0; t < T_; ++t) {
    const float* uslice = ug + (size_t)t * B_ * V_;
    int notLast = (t < T_ - 1) ? 1 : 0;
    // gh(h_{t+1}) -> ghP ; screen(h_{t+1}) -> scores loP_t + blockmax
    fusedA<<<896, 256, 0, stream>>>(h, Whh, hB, WoutB, bout, uslice,
                                    ghP, loP, bMax, notLast);
    // hoisted ghP sums ; pick tok_t via blockmax ; gates -> h_{t+2}
    fusedB<<<512, 256, 0, stream>>>(loP, bMax, h, Wout, bout, uslice, ghP, giP,
                                    bih, bhh, hB, toks, t, notLast);
  }

  // ---- assemble fp32 output ----
  kfinal32<<<40960, 256, 0, stream>>>(out, toks);
  if (!resolved) kmark_resolver<<<1, 64, 0, stream>>>(out);
}

// Round 21
// 917.604 us; speedup vs baseline: 1.1074x; 1.1074x over previous
//
#include <hip/hip_runtime.h>
#include <hip/hip_bf16.h>
#include <math.h>

#define B_ 512
#define E_ 256
#define H_ 512
#define V_ 4096
#define T_ 18
#define L_ 20
#define MARGIN_ 0.04f
#define CCAP_ 64

typedef __attribute__((ext_vector_type(8))) short bf16x8;
typedef __attribute__((ext_vector_type(4))) float f32x4;

// ========== prep: cat fp32 + WoutB bf16 (float4-vectorized) ==========
__global__ __launch_bounds__(256) void kprep32(const float* __restrict__ pa,
                                               const float* __restrict__ pb,
                                               const float* __restrict__ Wout,
                                               float* __restrict__ cat,
                                               __hip_bfloat16* __restrict__ WB) {
  int idx = blockIdx.x * 256 + threadIdx.x;      // < 655360 quads
  if (idx < 131072) {
    int e0 = idx * 4;
    int b = e0 >> 10, k = e0 & 1023;             // quads never straddle 512
    float4 v = (k < 512) ? *reinterpret_cast<const float4*>(pa + (size_t)b * 512 + k)
                         : *reinterpret_cast<const float4*>(pb + (size_t)b * 512 + (k - 512));
    *reinterpret_cast<float4*>(cat + e0) = v;
  } else {
    int e0 = (idx - 131072) * 4;                 // < 2097152
    float4 w = *reinterpret_cast<const float4*>(Wout + e0);
    __hip_bfloat16 b0 = __float2bfloat16(w.x), b1 = __float2bfloat16(w.y);
    __hip_bfloat16 b2 = __float2bfloat16(w.z), b3 = __float2bfloat16(w.w);
    ushort4 o;
    o.x = *reinterpret_cast<unsigned short*>(&b0);
    o.y = *reinterpret_cast<unsigned short*>(&b1);
    o.z = *reinterpret_cast<unsigned short*>(&b2);
    o.w = *reinterpret_cast<unsigned short*>(&b3);
    *reinterpret_cast<ushort4*>(WB + e0) = o;
  }
}

// ===== fp32 GEMM body, 128x64 tile (MxN), 8x4/thread, split-K (R9-proven) ===
// P[bz][M,N] slice: pOff = bz*My*128*N. lda = full K; kPer multiple of 16.
__device__ __forceinline__ void gemm64_body(const float* __restrict__ A,
                                            const float* __restrict__ W,
                                            float* __restrict__ P,
                                            int N, int lda, int kPer,
                                            int bx, int by, int bz, int My,
                                            int tid, char* smemRaw) {
  float (*As)[130] = reinterpret_cast<float(*)[130]>(smemRaw);          // 8320 B
  float (*Bs)[68]  = reinterpret_cast<float(*)[68]>(smemRaw + 8320);    // 4352 B
  const int tx = tid & 15, ty = tid >> 4;
  const int bn = bx * 64, bm = by * 128;
  const int k0 = bz * kPer;
  const size_t pOff = (size_t)bz * My * 128 * N;
  const int kk0 = tid & 15;
  const int ra0 = (tid >> 4) * 8;
  const int cb0 = (tid >> 4) * 4;

  float acc[8][4] = {};
  for (int kb = 0; kb < kPer; kb += 16) {
#pragma unroll
    for (int q = 0; q < 8; ++q)
      As[kk0][ra0 + q] = A[(size_t)(bm + ra0 + q) * lda + k0 + kb + kk0];
#pragma unroll
    for (int q = 0; q < 4; ++q)
      Bs[kk0][cb0 + q] = W[(size_t)(bn + cb0 + q) * lda + k0 + kb + kk0];
    __syncthreads();
#pragma unroll
    for (int kk = 0; kk < 16; ++kk) {
      float a[8], b[4];
#pragma unroll
      for (int i = 0; i < 8; ++i) a[i] = As[kk][ty + 16 * i];
#pragma unroll
      for (int j = 0; j < 4; ++j) b[j] = Bs[kk][tx + 16 * j];
#pragma unroll
      for (int i = 0; i < 8; ++i)
#pragma unroll
        for (int j = 0; j < 4; ++j) acc[i][j] = fmaf(a[i], b[j], acc[i][j]);
    }
    __syncthreads();
  }
#pragma unroll
  for (int i = 0; i < 8; ++i) {
    size_t r = (size_t)(bm + ty + 16 * i);
#pragma unroll
    for (int j = 0; j < 4; ++j)
      P[pOff + r * N + bn + tx + 16 * j] = acc[i][j];
  }
}

// ===== setup: h0P gemm (256 blk) + giP gemm (768 blk) in one launch =====
__global__ __launch_bounds__(256) void setupGemms(const float* __restrict__ cat,
                                                  const float* __restrict__ Winit,
                                                  float* __restrict__ h0P,
                                                  const float* __restrict__ emb,
                                                  const float* __restrict__ Wih,
                                                  float* __restrict__ giP) {
  __shared__ __align__(16) char smemRaw[12672];
  const int bid = blockIdx.x, tid = threadIdx.x;
  if (bid < 256) {
    // h0P: cat[512,1024] @ Winit[512,1024]^T, 128x64 tiles, split-K=8
    int bx = bid & 7, by = (bid >> 3) & 3, bz = bid >> 5;
    gemm64_body(cat, Winit, h0P, 512, 1024, 128, bx, by, bz, 4, tid, smemRaw);
  } else {
    // giP: emb[4096,256] @ Wih[1536,256]^T, 128x64 tiles, single chunk
    int gid = bid - 256;
    int bx = gid % 24, by = gid / 24;            // by in 0..31
    gemm64_body(emb, Wih, giP, 1536, 256, 256, bx, by, 0, 32, tid, smemRaw);
  }
}

// ===== standalone gh GEMM (setup step 0): 768 blocks =====
__global__ __launch_bounds__(256) void ghK(const float* __restrict__ h,
                                           const float* __restrict__ Whh,
                                           float* __restrict__ ghP) {
  __shared__ __align__(16) char smemRaw[12672];
  const int bid = blockIdx.x, tid = threadIdx.x;
  int bx = bid % 24, by = (bid / 24) & 3, bz = bid / 96;
  gemm64_body(h, Whh, ghP, 1536, 512, 64, bx, by, bz, 4, tid, smemRaw);
}

// ======== h0 = sum of 8 partials + b_init (fp64 sum); fp32 + bf16 out ======
__global__ __launch_bounds__(256) void reduceH0(const float* __restrict__ parts,
                                                const float* __restrict__ binit,
                                                float* __restrict__ h,
                                                __hip_bfloat16* __restrict__ hB) {
  int i = blockIdx.x * 256 + threadIdx.x;
  double s = (double)binit[i & 511];
#pragma unroll
  for (int c = 0; c < 8; ++c) s += (double)parts[(size_t)c * 262144 + i];
  float f = (float)s;
  h[i] = f;
  hB[i] = __float2bfloat16(f);
}

// ====== screen: bf16 MFMA -> raw logits to loP (R19 version) ======
__device__ __forceinline__ void screen_body(const __hip_bfloat16* __restrict__ hB,
                                            const __hip_bfloat16* __restrict__ WoutB,
                                            float* __restrict__ loP,
                                            int bid, int tid) {
  const int wave = tid >> 6, lane = tid & 63;
  const int bx = bid & 63, by = bid >> 6;
  const int bm = by * 64 + wave * 16;
  const int bn = bx * 64;
  const int rA = lane & 15, g = lane >> 4;
  const __hip_bfloat16* ha = hB + (size_t)(bm + rA) * H_ + g * 8;
  const __hip_bfloat16* wb = WoutB + (size_t)(bn + rA) * H_ + g * 8;
  f32x4 acc[4] = {};
  for (int k0 = 0; k0 < H_; k0 += 32) {
    bf16x8 a = *reinterpret_cast<const bf16x8*>(ha + k0);
#pragma unroll
    for (int j = 0; j < 4; ++j) {
      bf16x8 b = *reinterpret_cast<const bf16x8*>(wb + (size_t)j * 16 * H_ + k0);
      acc[j] = __builtin_amdgcn_mfma_f32_16x16x32_bf16(a, b, acc[j], 0, 0, 0);
    }
  }
#pragma unroll
  for (int j = 0; j < 4; ++j)
#pragma unroll
    for (int r = 0; r < 4; ++r)
      loP[(size_t)(bm + g * 4 + r) * V_ + bn + j * 16 + rA] = acc[j][r];
}

// ====== pick: wave-shfl reductions (R19-proven) ======
__device__ __forceinline__ int pick_body(const float* __restrict__ loP,
                                         const float* __restrict__ h,
                                         const float* __restrict__ Wout,
                                         const float* __restrict__ bout,
                                         const float* __restrict__ ub,
                                         int bid, int tid, char* smemRaw) {
  double* sd    = reinterpret_cast<double*>(smemRaw);        // 256*8 (rescore)
  int*    pre   = reinterpret_cast<int*>(smemRaw + 2048);    // 256*4 (rare scan)
  int*    candV = reinterpret_cast<int*>(smemRaw + 3072);    // 64*4
  float*  swv   = reinterpret_cast<float*>(smemRaw + 3328);  // 4
  int*    swi   = reinterpret_cast<int*>(smemRaw + 3344);    // 4
  int*    sct   = reinterpret_cast<int*>(smemRaw + 3360);    // 4
  double* bestS = reinterpret_cast<double*>(smemRaw + 3376); // 8
  int*    bestV = reinterpret_cast<int*>(smemRaw + 3384);    // 4
  const int lane = tid & 63, wv = tid >> 6;
  const float* l0 = loP + (size_t)bid * V_;
  float sloc[16];
  float best = -1e30f; int bi = 0x7fffffff;
#pragma unroll
  for (int i = 0; i < 16; ++i) {
    int v = tid + 256 * i;
    float s = l0[v] + bout[v] - logf(-logf(ub[v]));
    sloc[i] = s;
    if (s > best) { best = s; bi = v; }
  }
#pragma unroll
  for (int off = 1; off < 64; off <<= 1) {
    float ov = __shfl_xor(best, off, 64);
    int   oi = __shfl_xor(bi,  off, 64);
    if (ov > best || (ov == best && oi < bi)) { best = ov; bi = oi; }
  }
  if (lane == 0) { swv[wv] = best; swi[wv] = bi; }
  __syncthreads();
  float smax = swv[0]; int amax = swi[0];
#pragma unroll
  for (int w = 1; w < 4; ++w) {
    float ov = swv[w]; int oi = swi[w];
    if (ov > smax || (ov == smax && oi < amax)) { smax = ov; amax = oi; }
  }
  int c = 0;
#pragma unroll
  for (int i = 0; i < 16; ++i) if (sloc[i] >= smax - MARGIN_) ++c;
  int csum = c;
#pragma unroll
  for (int off = 1; off < 64; off <<= 1) csum += __shfl_xor(csum, off, 64);
  if (lane == 0) sct[wv] = csum;
  __syncthreads();
  int tot = sct[0] + sct[1] + sct[2] + sct[3];

  int tok;
  if (tot == 1) {
    tok = amax;                                   // screen error << margin
  } else if (tot <= CCAP_) {
    int lv[16];
    int cc = 0;
#pragma unroll
    for (int i = 0; i < 16; ++i)
      if (sloc[i] >= smax - MARGIN_) { if (cc < 16) lv[cc] = tid + 256 * i; ++cc; }
    pre[tid] = cc;
    __syncthreads();
    for (int off = 1; off < 256; off <<= 1) {
      int vv = (tid >= off) ? pre[tid - off] : 0;
      __syncthreads();
      pre[tid] += vv;
      __syncthreads();
    }
    int base = pre[tid] - cc;
    for (int q = 0; q < cc; ++q) candV[base + q] = lv[q];
    if (tid == 0) { *bestS = -1e300; *bestV = 0x7fffffff; }
    __syncthreads();
    const float* hb = h + (size_t)bid * H_;
    for (int ci = 0; ci < tot; ++ci) {
      int v = candV[ci];
      const float* wr = Wout + (size_t)v * H_;
      double p = (double)hb[tid] * (double)wr[tid]
               + (double)hb[tid + 256] * (double)wr[tid + 256];
#pragma unroll
      for (int off = 1; off < 64; off <<= 1) p += __shfl_xor(p, off, 64);
      if (lane == 0) sd[wv] = p;
      __syncthreads();
      if (tid == 0) {
        double s = sd[0] + sd[1] + sd[2] + sd[3]
                 + (double)bout[v] - log(-log((double)ub[v]));
        if (s > *bestS || (s == *bestS && v < *bestV)) { *bestS = s; *bestV = v; }
      }
      __syncthreads();
    }
    tok = *bestV;
  } else {
    const float* hb = h + (size_t)bid * H_;
    double dbest = -1e300; int dbi = 0x7fffffff;
    for (int i = 0; i < 16; ++i) {
      int v = tid + 256 * i;
      const float* wr = Wout + (size_t)v * H_;
      double dot = 0.0;
      for (int k = 0; k < H_; ++k) dot = fma((double)hb[k], (double)wr[k], dot);
      double s = dot + (double)bout[v] - log(-log((double)ub[v]));
      if (s > dbest) { dbest = s; dbi = v; }
    }
#pragma unroll
    for (int off = 1; off < 64; off <<= 1) {
      double od = __shfl_xor(dbest, off, 64);
      int    oi = __shfl_xor(dbi,  off, 64);
      if (od > dbest || (od == dbest && oi < dbi)) { dbest = od; dbi = oi; }
    }
    if (lane == 0) { sd[wv] = dbest; pre[wv] = dbi; }
    __syncthreads();
    double bs = sd[0]; int bv = pre[0];
#pragma unroll
    for (int w = 1; w < 4; ++w) {
      if (sd[w] > bs || (sd[w] == bs && pre[w] < bv)) { bs = sd[w]; bv = pre[w]; }
    }
    tok = bv;
  }
  return tok;
}

// ===== K0: standalone gates (initial step, tok = SOS) =====
__global__ __launch_bounds__(256) void gates_init(const float* __restrict__ ghP,
                                                  const float* __restrict__ giP,
                                                  const float* __restrict__ bih,
                                                  const float* __restrict__ bhh,
                                                  float* __restrict__ h,
                                                  __hip_bfloat16* __restrict__ hB) {
  const int bid = blockIdx.x, tid = threadIdx.x;
  const float* g0 = giP + (size_t)1 * 1536;
  size_t base = (size_t)bid * 1536;
#pragma unroll
  for (int c = 0; c < 2; ++c) {
    int j = c * 256 + tid;
    int idx = bid * 512 + j;
    double gr = (double)bhh[j], gz = (double)bhh[512 + j], gn = (double)bhh[1024 + j];
#pragma unroll
    for (int s = 0; s < 8; ++s) {
      const float* p = ghP + (size_t)s * 786432 + base;
      gr += (double)p[j]; gz += (double)p[512 + j]; gn += (double)p[1024 + j];
    }
    float ir  = g0[j]        + bih[j];
    float iz  = g0[512 + j]  + bih[512 + j];
    float inn = g0[1024 + j] + bih[1024 + j];
    float r = 1.f / (1.f + expf(-(ir + (float)gr)));
    float z = 1.f / (1.f + expf(-(iz + (float)gz)));
    float n = tanhf(inn + r * (float)gn);
    float hn = (1.f - z) * n + z * h[idx];
    h[idx] = hn;
    hB[idx] = __float2bfloat16(hn);
  }
}

// ===== K1: gh GEMM 128x64 tiles (blocks 0..767) + screen (768..1279) =====
__global__ __launch_bounds__(256) void fusedA(const float* __restrict__ h,
                                              const float* __restrict__ Whh,
                                              const __hip_bfloat16* __restrict__ hB,
                                              const __hip_bfloat16* __restrict__ WoutB,
                                              float* __restrict__ ghP,
                                              float* __restrict__ loP,
                                              int doGemm) {
  __shared__ __align__(16) char smemRaw[12672];
  const int bid = blockIdx.x, tid = threadIdx.x;
  if (bid < 768) {
    if (doGemm) {
      int bx = bid % 24, by = (bid / 24) & 3, bz = bid / 96;
      gemm64_body(h, Whh, ghP, 1536, 512, 64, bx, by, bz, 4, tid, smemRaw);
    }
  } else {
    screen_body(hB, WoutB, loP, bid - 768, tid);
  }
}

// ===== K2: hoisted ghP sums -> pick tok(t) -> finish gates(t+1) (R19) =====
__global__ __launch_bounds__(256) void fusedB(const float* __restrict__ loP,
                                              float* __restrict__ h,
                                              const float* __restrict__ Wout,
                                              const float* __restrict__ bout,
                                              const float* __restrict__ u,   // step slice
                                              const float* __restrict__ ghP,
                                              const float* __restrict__ giP,
                                              const float* __restrict__ bih,
                                              const float* __restrict__ bhh,
                                              __hip_bfloat16* __restrict__ hB,
                                              int* __restrict__ toks,
                                              int t, int doGates) {
  __shared__ __align__(16) char smemRaw[5440];
  const int bid = blockIdx.x, tid = threadIdx.x;
  const int j0 = tid, j1 = 256 + tid;
  double gr0 = (double)bhh[j0], gz0 = (double)bhh[512 + j0], gn0 = (double)bhh[1024 + j0];
  double gr1 = (double)bhh[j1], gz1 = (double)bhh[512 + j1], gn1 = (double)bhh[1024 + j1];
  if (doGates) {
    size_t base = (size_t)bid * 1536;
#pragma unroll
    for (int s = 0; s < 8; ++s) {
      const float* p = ghP + (size_t)s * 786432 + base;
      gr0 += (double)p[j0]; gz0 += (double)p[512 + j0]; gn0 += (double)p[1024 + j0];
      gr1 += (double)p[j1]; gz1 += (double)p[512 + j1]; gn1 += (double)p[1024 + j1];
    }
  }
  const float* ub = u + (size_t)bid * V_;
  int tok = pick_body(loP, h, Wout, bout, ub, bid, tid, smemRaw);
  if (tid == 0) toks[t * B_ + bid] = tok;
  if (doGates) {
    const float* g0 = giP + (size_t)tok * 1536;
    {
      int idx = bid * 512 + j0;
      float ir  = g0[j0]        + bih[j0];
      float iz  = g0[512 + j0]  + bih[512 + j0];
      float inn = g0[1024 + j0] + bih[1024 + j0];
      float r = 1.f / (1.f + expf(-(ir + (float)gr0)));
      float z = 1.f / (1.f + expf(-(iz + (float)gz0)));
      float n = tanhf(inn + r * (float)gn0);
      float hn = (1.f - z) * n + z * h[idx];
      h[idx] = hn;
      hB[idx] = __float2bfloat16(hn);
    }
    {
      int idx = bid * 512 + j1;
      float ir  = g0[j1]        + bih[j1];
      float iz  = g0[512 + j1]  + bih[512 + j1];
      float inn = g0[1024 + j1] + bih[1024 + j1];
      float r = 1.f / (1.f + expf(-(ir + (float)gr1)));
      float z = 1.f / (1.f + expf(-(iz + (float)gz1)));
      float n = tanhf(inn + r * (float)gn1);
      float hn = (1.f - z) * n + z * h[idx];
      h[idx] = hn;
      hB[idx] = __float2bfloat16(hn);
    }
  }
}

// ============== final: zero + one-hot scatter + SOS/EOS, fp32 ==============
__global__ __launch_bounds__(256) void kfinal32(float* __restrict__ out,
                                                const int* __restrict__ toks) {
  size_t c = (size_t)blockIdx.x * 256 + threadIdx.x;
  size_t e0 = c * 4;
  int v0 = (int)(e0 & (size_t)(V_ - 1));
  size_t row = e0 >> 12;
  int p = (int)(row % L_);
  int b = (int)(row / L_);
  int tok;
  if (p == 0)           tok = 1;
  else if (p == L_ - 1) tok = 2;
  else                  tok = toks[(p - 1) * B_ + b];
  float4 val = make_float4(0.f, 0.f, 0.f, 0.f);
  int d = tok - v0;
  if (d >= 0 && d < 4) {
    if (d == 0) val.x = 1.f; else if (d == 1) val.y = 1.f;
    else if (d == 2) val.z = 1.f; else val.w = 1.f;
  }
  reinterpret_cast<float4*>(out)[c] = val;
}

// ---------------- environment markers ----------------
__global__ void kmark_ws(float* out) {
  if (threadIdx.x == 0) out[0] = 16.0f;
}
__global__ void kmark_resolver(float* out) {
  if (threadIdx.x == 0) out[2] = 11.0f;
}

// ================================ launch ================================
extern "C" void kernel_launch(void* const* d_in, const int* in_sizes, int n_in,
                              void* d_out, int out_size, void* d_ws, size_t ws_size,
                              hipStream_t stream) {
  static const int EXPECT[12] = {262144, 262144, 524288, 512, 393216, 786432,
                                 1536, 1536, 2097152, 4096, 1048576, 37748736};
  const float* R[12];
  bool resolved = (n_in == 12);
  if (resolved) {
    bool used[12] = {};
    for (int i = 0; i < 12; ++i) {
      int f = -1;
      for (int j = 0; j < 12; ++j)
        if (!used[j] && in_sizes[j] == EXPECT[i]) { f = j; break; }
      if (f < 0) { resolved = false; break; }
      used[f] = true;
      R[i] = (const float*)d_in[f];
    }
  }
  if (!resolved)
    for (int i = 0; i < 12 && i < n_in; ++i) R[i] = (const float*)d_in[i];

  const float *pa = R[0], *pb = R[1], *Winit = R[2], *binit = R[3],
              *Wih = R[4], *Whh = R[5], *bih = R[6], *bhh = R[7],
              *Wout = R[8], *bout = R[9], *emb = R[10], *ug = R[11];
  float* out = (float*)d_out;

  const size_t TOK_BYTES = (size_t)T_ * B_ * sizeof(int);   // 36864
  if (ws_size < TOK_BYTES) { kmark_ws<<<1, 64, 0, stream>>>(out); return; }
  int* toks = (int*)d_ws;

  // scratch: h | giP | ghP(8 chunks; aliases cat+h0P pre-loop) | loP | hB | WoutB
  const size_t SC_FLOATS = 16121856;
  float* sc;
  if (ws_size >= 40960 + SC_FLOATS * sizeof(float)) {
    sc = (float*)((char*)d_ws + 40960);
  } else {
    sc = (float*)d_out;   // head of 167.8 MB out; kfinal32 rebuilds last
  }
  float* h    = sc;                                   // 262,144
  float* giP  = sc + 262144;                          // 6,291,456 (4096x1536)
  float* ghP  = sc + 6553600;                         // 6,291,456 (8 x 512x1536)
  float* loP  = sc + 12845056;                        // 2,097,152 (512x4096)
  __hip_bfloat16* hB    = (__hip_bfloat16*)(sc + 14942208);   // 262,144 bf16
  __hip_bfloat16* WoutB = (__hip_bfloat16*)(sc + 15073280);   // 2,097,152 bf16
  float* cat  = ghP;                                  // pre-loop only
  float* h0P  = ghP + 524288;                         // pre-loop only

  // ---- setup ----
  kprep32<<<2560, 256, 0, stream>>>(pa, pb, Wout, cat, WoutB);
  // h0P (256 blk) + giP (768 blk), one launch
  setupGemms<<<1024, 256, 0, stream>>>(cat, Winit, h0P, emb, Wih, giP);
  reduceH0<<<1024, 256, 0, stream>>>(h0P, binit, h, hB);
  // gh(h_0) then gates(SOS) -> h_1
  ghK<<<768, 256, 0, stream>>>(h, Whh, ghP);
  gates_init<<<512, 256, 0, stream>>>(ghP, giP, bih, bhh, h, hB);

  // ---- decode loop: 2 launches per step ----
  for (int t = 0; t < T_; ++t) {
    const float* uslice = ug + (size_t)t * B_ * V_;
    int notLast = (t < T_ - 1) ? 1 : 0;
    // gh(h_{t+1}) -> ghP (blocks 0..767); screen(h_{t+1}) -> loP_t (768..1279)
    fusedA<<<1280, 256, 0, stream>>>(h, Whh, hB, WoutB, ghP, loP, notLast);
    // hoisted ghP sums ; pick tok_t ; gates -> h_{t+2}
    fusedB<<<512, 256, 0, stream>>>(loP, h, Wout, bout, uslice, ghP, giP,
                                    bih, bhh, hB, toks, t, notLast);
  }

  // ---- assemble fp32 output ----
  kfinal32<<<40960, 256, 0, stream>>>(out, toks);
  if (!resolved) kmark_resolver<<<1, 64, 0, stream>>>(out);
}